// Round 11
// baseline (135.792 us; speedup 1.0000x reference)
//
#include <hip/hip_runtime.h>
#include <hip/hip_fp16.h>

// GLOBE_61864708931733 — R27: chunk loop split across blocks (8192 x 1-wave).
// R26 post-mortem (49.8us, -14%): 1-wave WGs cut idle 37k->17k cy/SIMD with
// VALU busy unchanged at 79k — pure scheduling win; granularity lever real.
// R27 doubles down: each block does ONE chunk (2 streams x 64 src). Grid
// 8192 = t(11b) | h | ch. Zero added total work: chunks already load
// disjoint weight copies, features are per-chunk, combine already atomic
// (2->4-way). Each sub-block uses its OWN ws copy (sub = 0..3; prep writes
// all 4) -> spreads L2. Serial wave length halves -> finer packing + shorter
// tail. Stagger machinery deleted (chunk-split IS the stagger).
// Predicted: idle 17k->~9k, globe 43-47us, VALUBusy 70-77%, Mfma ~21%.
// Neutral (48-51) => VALU issue floor (79k cy/SIMD) binding -> cut ops next.

#define N_T 2048
#define N_S 512
#define BLK 64
#define SCALE 2.885390081777927f   // 2*log2(e)

// d_ws: 4 copies, stride 5888 floats (23552 B):
//   units 0..21: f16x4-frag pairs, unit u = [64 lanes][16 B]
//     u 0..1:  W1 (unit0: mt0 lo / mt1 hi; unit1: mt2/mt3), kt=0 only
//     u 2..9:  W2' = -2*W2*SCALE: unit 2+mt*2+kp = K=32 frag (mt, kk=kp) f16x8
//     u 10..17: W3' same
//     u 18..19: Wout' hi | u 20..21: Wout' lo   (Wout' = -2*Wout, unscaled)
//   floats 5632..5823: scaled biases [3][64]; b2',b3' include +colsum(W)
//   floats 5824..5826: bout' = bout + colsum(Wout)  (unscaled)
#define CPY_F 5888     // floats per copy
#define CPY_U 1472     // 16B units per copy

typedef _Float16 f16;
typedef _Float16 f16x4 __attribute__((ext_vector_type(4)));
typedef _Float16 f16x8 __attribute__((ext_vector_type(8)));
typedef float f32x4 __attribute__((ext_vector_type(4)));
typedef unsigned short u16;
typedef unsigned int u32;

__device__ __forceinline__ float zsig(float x) {
    // x is SCALE*y; z = 1/(2^x+1); consumer weights are folded so t = 1-2z.
    float e = __builtin_amdgcn_exp2f(x);
    return __builtin_amdgcn_rcpf(e + 1.0f);
}

__device__ __forceinline__ f32x4 mfma16(f16x4 a, f16x4 b, f32x4 c) {
    return __builtin_amdgcn_mfma_f32_16x16x16f16(a, b, c, 0, 0, 0);
}
__device__ __forceinline__ f32x4 mfma32(f16x8 a, f16x8 b, f32x4 c) {
    return __builtin_amdgcn_mfma_f32_16x16x32_f16(a, b, c, 0, 0, 0);
}

__device__ __forceinline__ u32 pkrtz(float a, float b) {
    return __builtin_bit_cast(u32, __builtin_amdgcn_cvt_pkrtz(a, b));
}

__device__ __forceinline__ f16x4 lo4(uint4 g) {
    uint2 p; p.x = g.x; p.y = g.y;
    return __builtin_bit_cast(f16x4, p);
}
__device__ __forceinline__ f16x4 hi4(uint4 g) {
    uint2 p; p.x = g.z; p.y = g.w;
    return __builtin_bit_cast(f16x4, p);
}
__device__ __forceinline__ f16x8 all8(uint4 g) {
    return __builtin_bit_cast(f16x8, g);
}

// 8 z-sigmoids -> one K=32 B-frag (f16x8) built directly as a uint4.
__device__ __forceinline__ f16x8 tpack8(f32x4 cl, f32x4 ch) {
    uint4 p;
    p.x = pkrtz(zsig(cl[0]), zsig(cl[1]));
    p.y = pkrtz(zsig(cl[2]), zsig(cl[3]));
    p.z = pkrtz(zsig(ch[0]), zsig(ch[1]));
    p.w = pkrtz(zsig(ch[2]), zsig(ch[3]));
    return __builtin_bit_cast(f16x8, p);
}

__global__ __launch_bounds__(256) void prep_kernel(
    const float* __restrict__ W1, const float* __restrict__ b1,
    const float* __restrict__ W2, const float* __restrict__ b2,
    const float* __restrict__ W3, const float* __restrict__ b3,
    const float* __restrict__ Wout, const float* __restrict__ bout,
    float* __restrict__ ws, float* __restrict__ outp)
{
    const int tid = blockIdx.x * 256 + threadIdx.x;   // grid 33*256 = 8448
    if (tid < 8192) outp[tid] = 0.f;                  // zero out for atomics
    if (tid < 5632) {                                 // 4 copies * 22 units * 64
        const int cpy = tid / 1408;
        const int r   = tid - cpy * 1408;
        const int u   = r >> 6, lane = r & 63;
        const int q = lane >> 4, l15 = lane & 15;
        float x[8];
        bool lo = false;
        #pragma unroll
        for (int e = 0; e < 8; ++e) {
            const int half = e >> 2, j = e & 3;
            float v;
            if (u < 2) {                       // W1: kt=0; frags mt = u*2+half
                const int mt = u * 2 + half;
                const int k = q * 4 + j;
                v = (k < 7) ? W1[k * 64 + mt * 16 + l15] * SCALE : 0.f;
            } else if (u < 10) {               // W2' = -2*W2*SCALE
                const int idx = u - 2, mt = idx >> 1, kp = idx & 1;
                const int k = (kp * 2 + half) * 16 + q * 4 + j;
                v = -2.0f * W2[k * 64 + mt * 16 + l15] * SCALE;
            } else if (u < 18) {               // W3' = -2*W3*SCALE
                const int idx = u - 10, mt = idx >> 1, kp = idx & 1;
                const int k = (kp * 2 + half) * 16 + q * 4 + j;
                v = -2.0f * W3[k * 64 + mt * 16 + l15] * SCALE;
            } else {                           // Wout' hi (18,19) / lo (20,21)
                const int kp = (u - 18) & 1;
                const int k = (kp * 2 + half) * 16 + q * 4 + j;
                v = (l15 < 3) ? -2.0f * Wout[k * 3 + l15] : 0.f;
                lo = (u >= 20);
            }
            x[e] = v;
        }
        u16 outw[8];
        #pragma unroll
        for (int e = 0; e < 8; ++e) {
            const f16 h = (f16)x[e];
            const f16 val = lo ? (f16)(x[e] - (float)h) : h;
            outw[e] = __builtin_bit_cast(u16, val);
        }
        uint4 g;
        g.x = outw[0] | ((u32)outw[1] << 16);
        g.y = outw[2] | ((u32)outw[3] << 16);
        g.z = outw[4] | ((u32)outw[5] << 16);
        g.w = outw[6] | ((u32)outw[7] << 16);
        *(uint4*)((char*)ws + (size_t)cpy * CPY_F * 4 + (size_t)(u * 64 + lane) * 16) = g;
    } else if (tid < 6412) {                   // biases: 4 copies * 195
        const int b = tid - 5632;
        const int cpy = b / 195, i = b - cpy * 195;
        if (i < 192) {
            const int Lb = i >> 6, j = i & 63;
            float bv;
            if (Lb == 0) {
                bv = b1[j];
            } else if (Lb == 1) {              // b2' = b2 + colsum(W2)
                bv = b2[j];
                for (int k = 0; k < 64; ++k) bv += W2[k * 64 + j];
            } else {                           // b3' = b3 + colsum(W3)
                bv = b3[j];
                for (int k = 0; k < 64; ++k) bv += W3[k * 64 + j];
            }
            ws[cpy * CPY_F + 5632 + i] = bv * SCALE;
        } else {                               // bout' = bout + colsum(Wout)
            const int c3 = i - 192;            // 0..2
            float bv = bout[c3];
            for (int k = 0; k < 64; ++k) bv += Wout[k * 3 + c3];
            ws[cpy * CPY_F + 5824 + c3] = bv;  // unscaled
        }
    }
}

__global__ __launch_bounds__(BLK, 2) void globe_mfma(
    const float* __restrict__ pts, const float* __restrict__ ctr,
    const float* __restrict__ nrm, const float* __restrict__ areas,
    const float* __restrict__ rlen, const float* __restrict__ bout,
    const float* __restrict__ p_scale, const float* __restrict__ p_bias,
    const float* __restrict__ v_scale, const float* __restrict__ v_bias,
    const float* __restrict__ ws,
    float* __restrict__ out)
{
    __shared__ __align__(16) u16 featL[2][64][8];      // [stream]
    __shared__ __align__(16) uint4 geomL[2][64];

    const int lane = threadIdx.x & 63;
    const int l15  = lane & 15;
    const int q    = lane >> 4;
    const int qf   = q & 1;                          // clamped feature octet
    const int b    = blockIdx.x;                     // 8192 blocks
    const int t    = b >> 2;                         // target
    const int sub  = b & 3;                          // quarter: h=sub>>1, ch=sub&1
    const int h    = sub >> 1;
    const int ch   = sub & 1;

    const float px = pts[3 * t + 0], py = pts[3 * t + 1], pz = pts[3 * t + 2];
    const float invL0 = __builtin_amdgcn_rcpf(rlen[0]);
    const float invL1 = __builtin_amdgcn_rcpf(rlen[1]);
    f32x4 co_init = (f32x4){0.f, 0.f, 0.f, 0.f};
    if (q == 0) { co_init[0] = ws[5824]; co_init[1] = ws[5825]; co_init[2] = ws[5826]; }

    const f16x4 bz = (f16x4){0, 0, 0, 0};
    float accp = 0.f, avx = 0.f, avy = 0.f, avz = 0.f;

    // per-sub weight copy (all 4 prep copies used): spreads L2, defeats LICM
    const uint4* __restrict__ wsU = (const uint4*)ws + sub * CPY_U;
    const float* __restrict__ wsBias = ws + sub * CPY_F + 5632;

    // ---- features + geometry for BOTH streams ----
    #pragma unroll
    for (int st = 0; st < 2; ++st) {
        const int s = (h * 4 + ch * 2 + st) * 64 + lane;
        const float cx = ctr[3 * s + 0], cy = ctr[3 * s + 1], cz = ctr[3 * s + 2];
        const float snx = nrm[3 * s + 0], sny = nrm[3 * s + 1], snz = nrm[3 * s + 2];
        const float ar = areas[s];
        const float rvx = px - cx, rvy = py - cy, rvz = pz - cz;
        const float r2 = rvx * rvx + rvy * rvy + rvz * rvz;
        const float r2e = r2 + 1e-8f;
        const float rinv = __builtin_amdgcn_rsqf(r2e);
        const float r = r2e * rinv;
        const float rhx = rvx * rinv, rhy = rvy * rinv, rhz = rvz * rinv;
        const float cth = rhx * snx + rhy * sny + rhz * snz;
        const float c2 = cth * cth;
        const float decay = ar * __builtin_amdgcn_rcpf(r2 + 1.0f);
        uint4 fw;
        fw.x = pkrtz(__builtin_amdgcn_rcpf(fmaf(r, invL0, 1.0f)),
                     __builtin_amdgcn_rcpf(fmaf(r, invL1, 1.0f)));
        fw.y = pkrtz(1.0f, cth);
        fw.z = pkrtz(fmaf(1.5f, c2, -0.5f), cth * fmaf(2.5f, c2, -1.5f));
        fw.w = pkrtz(__logf(ar), 0.0f);
        *(uint4*)&featL[st][lane][0] = fw;
        uint4 g;
        g.x = __builtin_bit_cast(u32, decay);
        g.y = pkrtz(rhx, rhy);
        g.z = pkrtz(rhz, snx);
        g.w = pkrtz(sny, snz);
        geomL[st][lane] = g;
    }

    // ---- layer 1 (16x16x16, K=7 padded; shared frags, both streams) ----
    f16x8 B2[2][2][4];   // [stream][kk][n4]  (K=32 z-frags for layer 2)
    {
        const uint4 g0 = wsU[0 * 64 + lane], g1 = wsU[1 * 64 + lane];
        f16x4 a1[4];
        a1[0] = lo4(g0); a1[1] = hi4(g0); a1[2] = lo4(g1); a1[3] = hi4(g1);
        float4 bv[4];
        #pragma unroll
        for (int mt = 0; mt < 4; ++mt)
            bv[mt] = *(const float4*)(wsBias + 0 * 64 + mt * 16 + q * 4);
        #pragma unroll
        for (int n4 = 0; n4 < 4; ++n4) {
            f16x4 bf[2];
            #pragma unroll
            for (int st = 0; st < 2; ++st) {
                const f16x4 lv = *(const f16x4*)&featL[st][n4 * 16 + l15][qf * 4];
                bf[st] = (q < 2) ? lv : bz;
            }
            f32x4 c[2][4];
            #pragma unroll
            for (int mt = 0; mt < 4; ++mt) {
                c[0][mt] = (f32x4){bv[mt].x, bv[mt].y, bv[mt].z, bv[mt].w};
                c[1][mt] = c[0][mt];
                c[0][mt] = mfma16(a1[mt], bf[0], c[0][mt]);
                c[1][mt] = mfma16(a1[mt], bf[1], c[1][mt]);
            }
            #pragma unroll
            for (int kk = 0; kk < 2; ++kk) {
                B2[0][kk][n4] = tpack8(c[0][2 * kk], c[0][2 * kk + 1]);
                B2[1][kk][n4] = tpack8(c[1][2 * kk], c[1][2 * kk + 1]);
            }
        }
    }

    // ---- layer 2 (16x16x32) ----
    f16x8 B3[2][2][4];
    {
        f16x8 a[4][2];
        #pragma unroll
        for (int mt = 0; mt < 4; ++mt) {
            a[mt][0] = all8(wsU[(2 + 2 * mt) * 64 + lane]);
            a[mt][1] = all8(wsU[(3 + 2 * mt) * 64 + lane]);
        }
        float4 bv[4];
        #pragma unroll
        for (int mt = 0; mt < 4; ++mt)
            bv[mt] = *(const float4*)(wsBias + 1 * 64 + mt * 16 + q * 4);
        #pragma unroll
        for (int n4 = 0; n4 < 4; ++n4) {
            f32x4 c[2][4];
            #pragma unroll
            for (int mt = 0; mt < 4; ++mt) {
                c[0][mt] = (f32x4){bv[mt].x, bv[mt].y, bv[mt].z, bv[mt].w};
                c[1][mt] = c[0][mt];
            }
            #pragma unroll
            for (int kk = 0; kk < 2; ++kk)
                #pragma unroll
                for (int mt = 0; mt < 4; ++mt) {
                    c[0][mt] = mfma32(a[mt][kk], B2[0][kk][n4], c[0][mt]);
                    c[1][mt] = mfma32(a[mt][kk], B2[1][kk][n4], c[1][mt]);
                }
            #pragma unroll
            for (int kk = 0; kk < 2; ++kk) {
                B3[0][kk][n4] = tpack8(c[0][2 * kk], c[0][2 * kk + 1]);
                B3[1][kk][n4] = tpack8(c[1][2 * kk], c[1][2 * kk + 1]);
            }
        }
    }

    // ---- layer 3 (16x16x32) ----
    f16x8 BO[2][2][4];
    {
        f16x8 a[4][2];
        #pragma unroll
        for (int mt = 0; mt < 4; ++mt) {
            a[mt][0] = all8(wsU[(10 + 2 * mt) * 64 + lane]);
            a[mt][1] = all8(wsU[(11 + 2 * mt) * 64 + lane]);
        }
        float4 bv[4];
        #pragma unroll
        for (int mt = 0; mt < 4; ++mt)
            bv[mt] = *(const float4*)(wsBias + 2 * 64 + mt * 16 + q * 4);
        #pragma unroll
        for (int n4 = 0; n4 < 4; ++n4) {
            f32x4 c[2][4];
            #pragma unroll
            for (int mt = 0; mt < 4; ++mt) {
                c[0][mt] = (f32x4){bv[mt].x, bv[mt].y, bv[mt].z, bv[mt].w};
                c[1][mt] = c[0][mt];
            }
            #pragma unroll
            for (int kk = 0; kk < 2; ++kk)
                #pragma unroll
                for (int mt = 0; mt < 4; ++mt) {
                    c[0][mt] = mfma32(a[mt][kk], B3[0][kk][n4], c[0][mt]);
                    c[1][mt] = mfma32(a[mt][kk], B3[1][kk][n4], c[1][mt]);
                }
            #pragma unroll
            for (int kk = 0; kk < 2; ++kk) {
                BO[0][kk][n4] = tpack8(c[0][2 * kk], c[0][2 * kk + 1]);
                BO[1][kk][n4] = tpack8(c[1][2 * kk], c[1][2 * kk + 1]);
            }
        }
    }

    // ---- output layer (16x16x32, hi+lo) + decay-weighted accumulation ----
    {
        const f16x8 aoh0 = all8(wsU[18 * 64 + lane]);
        const f16x8 aoh1 = all8(wsU[19 * 64 + lane]);
        const f16x8 aol0 = all8(wsU[20 * 64 + lane]);
        const f16x8 aol1 = all8(wsU[21 * 64 + lane]);
        #pragma unroll
        for (int n4 = 0; n4 < 4; ++n4) {
            f32x4 co[2];
            co[0] = co_init; co[1] = co_init;
            co[0] = mfma32(aoh0, BO[0][0][n4], co[0]);
            co[1] = mfma32(aoh0, BO[1][0][n4], co[1]);
            co[0] = mfma32(aol0, BO[0][0][n4], co[0]);
            co[1] = mfma32(aol0, BO[1][0][n4], co[1]);
            co[0] = mfma32(aoh1, BO[0][1][n4], co[0]);
            co[1] = mfma32(aoh1, BO[1][1][n4], co[1]);
            co[0] = mfma32(aol1, BO[0][1][n4], co[0]);
            co[1] = mfma32(aol1, BO[1][1][n4], co[1]);
            if (q == 0) {
                #pragma unroll
                for (int st = 0; st < 2; ++st) {
                    const uint4 g = geomL[st][n4 * 16 + l15];
                    const float d = __builtin_bit_cast(float, g.x);
                    const float2 rxy = __half22float2(__builtin_bit_cast(__half2, g.y));
                    const float2 rzx = __half22float2(__builtin_bit_cast(__half2, g.z));
                    const float2 nyz = __half22float2(__builtin_bit_cast(__half2, g.w));
                    const float o0 = co[st][0], o1 = co[st][1], o2 = co[st][2];
                    accp = fmaf(o0, d, accp);
                    avx  = fmaf(fmaf(o1, rxy.x, o2 * rzx.y), d, avx);
                    avy  = fmaf(fmaf(o1, rxy.y, o2 * nyz.x), d, avy);
                    avz  = fmaf(fmaf(o1, rzx.x, o2 * nyz.y), d, avz);
                }
            }
        }
    }

    // ---- reduce across the 16 accumulating lanes ----
    #pragma unroll
    for (int off = 8; off > 0; off >>= 1) {
        accp += __shfl_down(accp, off);
        avx  += __shfl_down(avx,  off);
        avy  += __shfl_down(avy,  off);
        avz  += __shfl_down(avz,  off);
    }

    // ---- combine across the 4 sub-blocks via atomics (out pre-zeroed) ----
    if (lane == 0) {
        const float ps = p_scale[0], vs = v_scale[0];
        const float bp = (sub == 0) ? p_bias[0] : 0.f;
        const float bv = (sub == 0) ? v_bias[0] : 0.f;
        atomicAdd(&out[4 * t + 0], fmaf(accp, ps, bp));
        atomicAdd(&out[4 * t + 1], fmaf(avx, vs, bv));
        atomicAdd(&out[4 * t + 2], fmaf(avy, vs, bv));
        atomicAdd(&out[4 * t + 3], fmaf(avz, vs, bv));
    }
}

extern "C" void kernel_launch(void* const* d_in, const int* in_sizes, int n_in,
                              void* d_out, int out_size, void* d_ws, size_t ws_size,
                              hipStream_t stream) {
    (void)in_sizes; (void)n_in; (void)ws_size; (void)out_size;
    const float* pts   = (const float*)d_in[0];
    const float* ctr   = (const float*)d_in[1];
    const float* nrm   = (const float*)d_in[2];
    const float* areas = (const float*)d_in[3];
    const float* rlen  = (const float*)d_in[4];
    const float* W1    = (const float*)d_in[5];
    const float* b1    = (const float*)d_in[6];
    const float* W2    = (const float*)d_in[7];
    const float* b2    = (const float*)d_in[8];
    const float* W3    = (const float*)d_in[9];
    const float* b3    = (const float*)d_in[10];
    const float* Wout  = (const float*)d_in[11];
    const float* bout  = (const float*)d_in[12];
    const float* ps    = (const float*)d_in[13];
    const float* pb    = (const float*)d_in[14];
    const float* vs    = (const float*)d_in[15];
    const float* vb    = (const float*)d_in[16];
    float* ws = (float*)d_ws;

    prep_kernel<<<33, 256, 0, stream>>>(W1, b1, W2, b2, W3, b3, Wout, bout, ws,
                                        (float*)d_out);
    globe_mfma<<<N_T * 4, BLK, 0, stream>>>(
        pts, ctr, nrm, areas, rlen, bout, ps, pb, vs, vb, ws, (float*)d_out);
}

// Round 12
// 130.186 us; speedup vs baseline: 1.0431x; 1.0431x over previous
//
#include <hip/hip_runtime.h>
#include <hip/hip_fp16.h>

// GLOBE_61864708931733 — R28: R26 + full unroll of the 2-chunk loop.
// R27 post-mortem (54.4us, regression): chunk-split doubled per-wave fixed
// costs (prologue/epilogue, 4-way cross-XCD atomics, wave tails); idle rose
// 17k->24k. Granularity optimum = R26 (1 wave x 2 chunks); both neighbors
// now measured worse. R26 residual: idle 16.7k cy/SIMD = in-wave phase-
// boundary stalls at ~2.4 resident waves/SIMD.
// R28 isolated change: remove the `#pragma unroll 1` fence -> compiler sees
// both chunk bodies, can hoist chunk1's feature/weight loads under chunk0's
// compute (cross-chunk ILP). Anti-LICM preserved (chunks read different ws
// copies). Everything else byte-identical to R26.
// Predicted: idle ->10-13k, globe 46-48.5us, VGPR 112-128, absmax 0.25.
// Neutral (49-51, VGPR@128) => register-bound, R26 converged. Spill
// (FETCH>>1MB) => revert.

#define N_T 2048
#define N_S 512
#define BLK 64
#define SCALE 2.885390081777927f   // 2*log2(e)

// d_ws: 4 copies, stride 5888 floats (23552 B):
//   units 0..21: f16x4-frag pairs, unit u = [64 lanes][16 B]
//     u 0..1:  W1 (unit0: mt0 lo / mt1 hi; unit1: mt2/mt3), kt=0 only
//     u 2..9:  W2' = -2*W2*SCALE: unit 2+mt*2+kp = K=32 frag (mt, kk=kp) f16x8
//     u 10..17: W3' same
//     u 18..19: Wout' hi | u 20..21: Wout' lo   (Wout' = -2*Wout, unscaled)
//   floats 5632..5823: scaled biases [3][64]; b2',b3' include +colsum(W)
//   floats 5824..5826: bout' = bout + colsum(Wout)  (unscaled)
#define CPY_F 5888     // floats per copy
#define CPY_U 1472     // 16B units per copy

typedef _Float16 f16;
typedef _Float16 f16x4 __attribute__((ext_vector_type(4)));
typedef _Float16 f16x8 __attribute__((ext_vector_type(8)));
typedef float f32x4 __attribute__((ext_vector_type(4)));
typedef unsigned short u16;
typedef unsigned int u32;

__device__ __forceinline__ float zsig(float x) {
    // x is SCALE*y; z = 1/(2^x+1); consumer weights are folded so t = 1-2z.
    float e = __builtin_amdgcn_exp2f(x);
    return __builtin_amdgcn_rcpf(e + 1.0f);
}

__device__ __forceinline__ f32x4 mfma16(f16x4 a, f16x4 b, f32x4 c) {
    return __builtin_amdgcn_mfma_f32_16x16x16f16(a, b, c, 0, 0, 0);
}
__device__ __forceinline__ f32x4 mfma32(f16x8 a, f16x8 b, f32x4 c) {
    return __builtin_amdgcn_mfma_f32_16x16x32_f16(a, b, c, 0, 0, 0);
}

__device__ __forceinline__ u32 pkrtz(float a, float b) {
    return __builtin_bit_cast(u32, __builtin_amdgcn_cvt_pkrtz(a, b));
}

__device__ __forceinline__ f16x4 lo4(uint4 g) {
    uint2 p; p.x = g.x; p.y = g.y;
    return __builtin_bit_cast(f16x4, p);
}
__device__ __forceinline__ f16x4 hi4(uint4 g) {
    uint2 p; p.x = g.z; p.y = g.w;
    return __builtin_bit_cast(f16x4, p);
}
__device__ __forceinline__ f16x8 all8(uint4 g) {
    return __builtin_bit_cast(f16x8, g);
}

// 8 z-sigmoids -> one K=32 B-frag (f16x8) built directly as a uint4.
__device__ __forceinline__ f16x8 tpack8(f32x4 cl, f32x4 ch) {
    uint4 p;
    p.x = pkrtz(zsig(cl[0]), zsig(cl[1]));
    p.y = pkrtz(zsig(cl[2]), zsig(cl[3]));
    p.z = pkrtz(zsig(ch[0]), zsig(ch[1]));
    p.w = pkrtz(zsig(ch[2]), zsig(ch[3]));
    return __builtin_bit_cast(f16x8, p);
}

__global__ __launch_bounds__(256) void prep_kernel(
    const float* __restrict__ W1, const float* __restrict__ b1,
    const float* __restrict__ W2, const float* __restrict__ b2,
    const float* __restrict__ W3, const float* __restrict__ b3,
    const float* __restrict__ Wout, const float* __restrict__ bout,
    float* __restrict__ ws, float* __restrict__ outp)
{
    const int tid = blockIdx.x * 256 + threadIdx.x;   // grid 33*256 = 8448
    if (tid < 8192) outp[tid] = 0.f;                  // zero out for atomics
    if (tid < 5632) {                                 // 4 copies * 22 units * 64
        const int cpy = tid / 1408;
        const int r   = tid - cpy * 1408;
        const int u   = r >> 6, lane = r & 63;
        const int q = lane >> 4, l15 = lane & 15;
        float x[8];
        bool lo = false;
        #pragma unroll
        for (int e = 0; e < 8; ++e) {
            const int half = e >> 2, j = e & 3;
            float v;
            if (u < 2) {                       // W1: kt=0; frags mt = u*2+half
                const int mt = u * 2 + half;
                const int k = q * 4 + j;
                v = (k < 7) ? W1[k * 64 + mt * 16 + l15] * SCALE : 0.f;
            } else if (u < 10) {               // W2' = -2*W2*SCALE
                const int idx = u - 2, mt = idx >> 1, kp = idx & 1;
                const int k = (kp * 2 + half) * 16 + q * 4 + j;
                v = -2.0f * W2[k * 64 + mt * 16 + l15] * SCALE;
            } else if (u < 18) {               // W3' = -2*W3*SCALE
                const int idx = u - 10, mt = idx >> 1, kp = idx & 1;
                const int k = (kp * 2 + half) * 16 + q * 4 + j;
                v = -2.0f * W3[k * 64 + mt * 16 + l15] * SCALE;
            } else {                           // Wout' hi (18,19) / lo (20,21)
                const int kp = (u - 18) & 1;
                const int k = (kp * 2 + half) * 16 + q * 4 + j;
                v = (l15 < 3) ? -2.0f * Wout[k * 3 + l15] : 0.f;
                lo = (u >= 20);
            }
            x[e] = v;
        }
        u16 outw[8];
        #pragma unroll
        for (int e = 0; e < 8; ++e) {
            const f16 h = (f16)x[e];
            const f16 val = lo ? (f16)(x[e] - (float)h) : h;
            outw[e] = __builtin_bit_cast(u16, val);
        }
        uint4 g;
        g.x = outw[0] | ((u32)outw[1] << 16);
        g.y = outw[2] | ((u32)outw[3] << 16);
        g.z = outw[4] | ((u32)outw[5] << 16);
        g.w = outw[6] | ((u32)outw[7] << 16);
        *(uint4*)((char*)ws + (size_t)cpy * CPY_F * 4 + (size_t)(u * 64 + lane) * 16) = g;
    } else if (tid < 6412) {                   // biases: 4 copies * 195
        const int b = tid - 5632;
        const int cpy = b / 195, i = b - cpy * 195;
        if (i < 192) {
            const int Lb = i >> 6, j = i & 63;
            float bv;
            if (Lb == 0) {
                bv = b1[j];
            } else if (Lb == 1) {              // b2' = b2 + colsum(W2)
                bv = b2[j];
                for (int k = 0; k < 64; ++k) bv += W2[k * 64 + j];
            } else {                           // b3' = b3 + colsum(W3)
                bv = b3[j];
                for (int k = 0; k < 64; ++k) bv += W3[k * 64 + j];
            }
            ws[cpy * CPY_F + 5632 + i] = bv * SCALE;
        } else {                               // bout' = bout + colsum(Wout)
            const int c3 = i - 192;            // 0..2
            float bv = bout[c3];
            for (int k = 0; k < 64; ++k) bv += Wout[k * 3 + c3];
            ws[cpy * CPY_F + 5824 + c3] = bv;  // unscaled
        }
    }
}

__global__ __launch_bounds__(BLK, 2) void globe_mfma(
    const float* __restrict__ pts, const float* __restrict__ ctr,
    const float* __restrict__ nrm, const float* __restrict__ areas,
    const float* __restrict__ rlen, const float* __restrict__ bout,
    const float* __restrict__ p_scale, const float* __restrict__ p_bias,
    const float* __restrict__ v_scale, const float* __restrict__ v_bias,
    const float* __restrict__ ws,
    float* __restrict__ out)
{
    __shared__ __align__(16) u16 featL[2][2][64][8];   // [chunk][stream]
    __shared__ __align__(16) uint4 geomL[2][2][64];

    const int lane = threadIdx.x & 63;
    const int l15  = lane & 15;
    const int q    = lane >> 4;
    const int qf   = q & 1;                          // clamped feature octet
    const int b    = blockIdx.x;                     // 4096 blocks
    const int t    = b >> 1;                         // target
    const int h    = b & 1;                          // source half

    const float px = pts[3 * t + 0], py = pts[3 * t + 1], pz = pts[3 * t + 2];
    const float invL0 = __builtin_amdgcn_rcpf(rlen[0]);
    const float invL1 = __builtin_amdgcn_rcpf(rlen[1]);
    f32x4 co_init = (f32x4){0.f, 0.f, 0.f, 0.f};
    if (q == 0) { co_init[0] = ws[5824]; co_init[1] = ws[5825]; co_init[2] = ws[5826]; }

    const f16x4 bz = (f16x4){0, 0, 0, 0};
    float accp = 0.f, avx = 0.f, avy = 0.f, avz = 0.f;

    const int stag = (h + t) & 1;                    // phase stagger

    #pragma unroll
    for (int cc = 0; cc < 2; ++cc) {
        const int ch = cc ^ stag;
        // chunk-dependent weight copy (copies 0,2 used): defeats LICM
        const uint4* __restrict__ wsU = (const uint4*)ws + (ch * 2) * CPY_U;
        const float* __restrict__ wsBias = ws + (ch * 2) * CPY_F + 5632;

        // ---- features + geometry for BOTH streams ----
        #pragma unroll
        for (int st = 0; st < 2; ++st) {
            const int s = (h * 4 + ch * 2 + st) * 64 + lane;
            const float cx = ctr[3 * s + 0], cy = ctr[3 * s + 1], cz = ctr[3 * s + 2];
            const float snx = nrm[3 * s + 0], sny = nrm[3 * s + 1], snz = nrm[3 * s + 2];
            const float ar = areas[s];
            const float rvx = px - cx, rvy = py - cy, rvz = pz - cz;
            const float r2 = rvx * rvx + rvy * rvy + rvz * rvz;
            const float r2e = r2 + 1e-8f;
            const float rinv = __builtin_amdgcn_rsqf(r2e);
            const float r = r2e * rinv;
            const float rhx = rvx * rinv, rhy = rvy * rinv, rhz = rvz * rinv;
            const float cth = rhx * snx + rhy * sny + rhz * snz;
            const float c2 = cth * cth;
            const float decay = ar * __builtin_amdgcn_rcpf(r2 + 1.0f);
            uint4 fw;
            fw.x = pkrtz(__builtin_amdgcn_rcpf(fmaf(r, invL0, 1.0f)),
                         __builtin_amdgcn_rcpf(fmaf(r, invL1, 1.0f)));
            fw.y = pkrtz(1.0f, cth);
            fw.z = pkrtz(fmaf(1.5f, c2, -0.5f), cth * fmaf(2.5f, c2, -1.5f));
            fw.w = pkrtz(__logf(ar), 0.0f);
            *(uint4*)&featL[cc][st][lane][0] = fw;
            uint4 g;
            g.x = __builtin_bit_cast(u32, decay);
            g.y = pkrtz(rhx, rhy);
            g.z = pkrtz(rhz, snx);
            g.w = pkrtz(sny, snz);
            geomL[cc][st][lane] = g;
        }

        // ---- layer 1 (16x16x16, K=7 padded; shared frags, both streams) ----
        f16x8 B2[2][2][4];   // [stream][kk][n4]  (K=32 z-frags for layer 2)
        {
            const uint4 g0 = wsU[0 * 64 + lane], g1 = wsU[1 * 64 + lane];
            f16x4 a1[4];
            a1[0] = lo4(g0); a1[1] = hi4(g0); a1[2] = lo4(g1); a1[3] = hi4(g1);
            float4 bv[4];
            #pragma unroll
            for (int mt = 0; mt < 4; ++mt)
                bv[mt] = *(const float4*)(wsBias + 0 * 64 + mt * 16 + q * 4);
            #pragma unroll
            for (int n4 = 0; n4 < 4; ++n4) {
                f16x4 bf[2];
                #pragma unroll
                for (int st = 0; st < 2; ++st) {
                    const f16x4 lv = *(const f16x4*)&featL[cc][st][n4 * 16 + l15][qf * 4];
                    bf[st] = (q < 2) ? lv : bz;
                }
                f32x4 c[2][4];
                #pragma unroll
                for (int mt = 0; mt < 4; ++mt) {
                    c[0][mt] = (f32x4){bv[mt].x, bv[mt].y, bv[mt].z, bv[mt].w};
                    c[1][mt] = c[0][mt];
                    c[0][mt] = mfma16(a1[mt], bf[0], c[0][mt]);
                    c[1][mt] = mfma16(a1[mt], bf[1], c[1][mt]);
                }
                #pragma unroll
                for (int kk = 0; kk < 2; ++kk) {
                    B2[0][kk][n4] = tpack8(c[0][2 * kk], c[0][2 * kk + 1]);
                    B2[1][kk][n4] = tpack8(c[1][2 * kk], c[1][2 * kk + 1]);
                }
            }
        }

        // ---- layer 2 (16x16x32) ----
        f16x8 B3[2][2][4];
        {
            f16x8 a[4][2];
            #pragma unroll
            for (int mt = 0; mt < 4; ++mt) {
                a[mt][0] = all8(wsU[(2 + 2 * mt) * 64 + lane]);
                a[mt][1] = all8(wsU[(3 + 2 * mt) * 64 + lane]);
            }
            float4 bv[4];
            #pragma unroll
            for (int mt = 0; mt < 4; ++mt)
                bv[mt] = *(const float4*)(wsBias + 1 * 64 + mt * 16 + q * 4);
            #pragma unroll
            for (int n4 = 0; n4 < 4; ++n4) {
                f32x4 c[2][4];
                #pragma unroll
                for (int mt = 0; mt < 4; ++mt) {
                    c[0][mt] = (f32x4){bv[mt].x, bv[mt].y, bv[mt].z, bv[mt].w};
                    c[1][mt] = c[0][mt];
                }
                #pragma unroll
                for (int kk = 0; kk < 2; ++kk)
                    #pragma unroll
                    for (int mt = 0; mt < 4; ++mt) {
                        c[0][mt] = mfma32(a[mt][kk], B2[0][kk][n4], c[0][mt]);
                        c[1][mt] = mfma32(a[mt][kk], B2[1][kk][n4], c[1][mt]);
                    }
                #pragma unroll
                for (int kk = 0; kk < 2; ++kk) {
                    B3[0][kk][n4] = tpack8(c[0][2 * kk], c[0][2 * kk + 1]);
                    B3[1][kk][n4] = tpack8(c[1][2 * kk], c[1][2 * kk + 1]);
                }
            }
        }

        // ---- layer 3 (16x16x32) ----
        f16x8 BO[2][2][4];
        {
            f16x8 a[4][2];
            #pragma unroll
            for (int mt = 0; mt < 4; ++mt) {
                a[mt][0] = all8(wsU[(10 + 2 * mt) * 64 + lane]);
                a[mt][1] = all8(wsU[(11 + 2 * mt) * 64 + lane]);
            }
            float4 bv[4];
            #pragma unroll
            for (int mt = 0; mt < 4; ++mt)
                bv[mt] = *(const float4*)(wsBias + 2 * 64 + mt * 16 + q * 4);
            #pragma unroll
            for (int n4 = 0; n4 < 4; ++n4) {
                f32x4 c[2][4];
                #pragma unroll
                for (int mt = 0; mt < 4; ++mt) {
                    c[0][mt] = (f32x4){bv[mt].x, bv[mt].y, bv[mt].z, bv[mt].w};
                    c[1][mt] = c[0][mt];
                }
                #pragma unroll
                for (int kk = 0; kk < 2; ++kk)
                    #pragma unroll
                    for (int mt = 0; mt < 4; ++mt) {
                        c[0][mt] = mfma32(a[mt][kk], B3[0][kk][n4], c[0][mt]);
                        c[1][mt] = mfma32(a[mt][kk], B3[1][kk][n4], c[1][mt]);
                    }
                #pragma unroll
                for (int kk = 0; kk < 2; ++kk) {
                    BO[0][kk][n4] = tpack8(c[0][2 * kk], c[0][2 * kk + 1]);
                    BO[1][kk][n4] = tpack8(c[1][2 * kk], c[1][2 * kk + 1]);
                }
            }
        }

        // ---- output layer (16x16x32, hi+lo) + decay-weighted accumulation ----
        {
            const f16x8 aoh0 = all8(wsU[18 * 64 + lane]);
            const f16x8 aoh1 = all8(wsU[19 * 64 + lane]);
            const f16x8 aol0 = all8(wsU[20 * 64 + lane]);
            const f16x8 aol1 = all8(wsU[21 * 64 + lane]);
            #pragma unroll
            for (int n4 = 0; n4 < 4; ++n4) {
                f32x4 co[2];
                co[0] = co_init; co[1] = co_init;
                co[0] = mfma32(aoh0, BO[0][0][n4], co[0]);
                co[1] = mfma32(aoh0, BO[1][0][n4], co[1]);
                co[0] = mfma32(aol0, BO[0][0][n4], co[0]);
                co[1] = mfma32(aol0, BO[1][0][n4], co[1]);
                co[0] = mfma32(aoh1, BO[0][1][n4], co[0]);
                co[1] = mfma32(aoh1, BO[1][1][n4], co[1]);
                co[0] = mfma32(aol1, BO[0][1][n4], co[0]);
                co[1] = mfma32(aol1, BO[1][1][n4], co[1]);
                if (q == 0) {
                    #pragma unroll
                    for (int st = 0; st < 2; ++st) {
                        const uint4 g = geomL[cc][st][n4 * 16 + l15];
                        const float d = __builtin_bit_cast(float, g.x);
                        const float2 rxy = __half22float2(__builtin_bit_cast(__half2, g.y));
                        const float2 rzx = __half22float2(__builtin_bit_cast(__half2, g.z));
                        const float2 nyz = __half22float2(__builtin_bit_cast(__half2, g.w));
                        const float o0 = co[st][0], o1 = co[st][1], o2 = co[st][2];
                        accp = fmaf(o0, d, accp);
                        avx  = fmaf(fmaf(o1, rxy.x, o2 * rzx.y), d, avx);
                        avy  = fmaf(fmaf(o1, rxy.y, o2 * nyz.x), d, avy);
                        avz  = fmaf(fmaf(o1, rzx.x, o2 * nyz.y), d, avz);
                    }
                }
            }
        }
    }

    // ---- reduce across the 16 accumulating lanes ----
    #pragma unroll
    for (int off = 8; off > 0; off >>= 1) {
        accp += __shfl_down(accp, off);
        avx  += __shfl_down(avx,  off);
        avy  += __shfl_down(avy,  off);
        avz  += __shfl_down(avz,  off);
    }

    // ---- combine across the two half-blocks via atomics (out pre-zeroed) ----
    if (lane == 0) {
        const float ps = p_scale[0], vs = v_scale[0];
        const float bp = h ? 0.f : p_bias[0];
        const float bv = h ? 0.f : v_bias[0];
        atomicAdd(&out[4 * t + 0], fmaf(accp, ps, bp));
        atomicAdd(&out[4 * t + 1], fmaf(avx, vs, bv));
        atomicAdd(&out[4 * t + 2], fmaf(avy, vs, bv));
        atomicAdd(&out[4 * t + 3], fmaf(avz, vs, bv));
    }
}

extern "C" void kernel_launch(void* const* d_in, const int* in_sizes, int n_in,
                              void* d_out, int out_size, void* d_ws, size_t ws_size,
                              hipStream_t stream) {
    (void)in_sizes; (void)n_in; (void)ws_size; (void)out_size;
    const float* pts   = (const float*)d_in[0];
    const float* ctr   = (const float*)d_in[1];
    const float* nrm   = (const float*)d_in[2];
    const float* areas = (const float*)d_in[3];
    const float* rlen  = (const float*)d_in[4];
    const float* W1    = (const float*)d_in[5];
    const float* b1    = (const float*)d_in[6];
    const float* W2    = (const float*)d_in[7];
    const float* b2    = (const float*)d_in[8];
    const float* W3    = (const float*)d_in[9];
    const float* b3    = (const float*)d_in[10];
    const float* Wout  = (const float*)d_in[11];
    const float* bout  = (const float*)d_in[12];
    const float* ps    = (const float*)d_in[13];
    const float* pb    = (const float*)d_in[14];
    const float* vs    = (const float*)d_in[15];
    const float* vb    = (const float*)d_in[16];
    float* ws = (float*)d_ws;

    prep_kernel<<<33, 256, 0, stream>>>(W1, b1, W2, b2, W3, b3, Wout, bout, ws,
                                        (float*)d_out);
    globe_mfma<<<N_T * 2, BLK, 0, stream>>>(
        pts, ctr, nrm, areas, rlen, bout, ps, pb, vs, vb, ws, (float*)d_out);
}